// Round 13
// baseline (159.535 us; speedup 1.0000x reference)
//
#include <hip/hip_runtime.h>

#define B_ 4
#define N_ 4096
#define C_ 256
#define M_ 2048

typedef __attribute__((ext_vector_type(8))) short short8;
typedef __attribute__((ext_vector_type(4))) short short4v;
typedef __attribute__((ext_vector_type(4))) float f32x4;

union U16x8 { uint4 u4; unsigned short us[8]; short8 s8; };
union U16x4 { uint2 u2; unsigned short us[4]; short4v s4; };

__device__ __forceinline__ float bf2f(unsigned short h) {
    unsigned int u = ((unsigned int)h) << 16;
    return __builtin_bit_cast(float, u);
}
__device__ __forceinline__ unsigned short f2bf(float f) {
    unsigned int u = __builtin_bit_cast(unsigned int, f);
    u += 0x7FFFu + ((u >> 16) & 1u);
    return (unsigned short)(u >> 16);
}

// 16x16x16 bf16 MFMA: builtin if available, else raw encoding via inline asm.
__device__ __forceinline__ f32x4 mfma16x16(short4v a, short4v b, f32x4 c) {
#if __has_builtin(__builtin_amdgcn_mfma_f32_16x16x16bf16_1k)
    return __builtin_amdgcn_mfma_f32_16x16x16bf16_1k(a, b, c, 0, 0, 0);
#else
    asm("v_mfma_f32_16x16x16_bf16 %0, %1, %2, %0" : "+v"(c) : "v"(a), "v"(b));
    return c;
#endif
}

// ---- Fused prepass: norms + casts into FRAGMENT-LINEAR layouts. ----
// grid (M/64, B), 1024 thr. Per batch (1 MB each):
//   gmc2[t][kk][key64][quad]  : 8 bf16 (16B) = ghat[key=t*64+key64][c=kk*32+quad*8 ..+8]
//       idx = t*16384 + kk*2048 + key64*32 + quad*8
//   gcm2[t][ct][khq][cr][quad]: 4 bf16 (8B)  = graw[c=ct*16+cr][key=t*64+khq*16+quad*4 ..+4]
//       idx = t*16384 + ct*1024 + khq*256 + cr*16 + quad*4
__global__ __launch_bounds__(1024) void k_prep(const float* __restrict__ g,
                                               unsigned short* __restrict__ gcm2,
                                               unsigned short* __restrict__ gmc2) {
    __shared__ float red[16][64];
    __shared__ float sInv[64];
    __shared__ unsigned short T[64 * 66];   // normalized [c][m] tile, odd-dword stride
    const int b = blockIdx.y, m0 = blockIdx.x * 64;
    const int tid = threadIdx.x;                // 0..1023
    const int ml = tid & 63, cq = tid >> 6;     // cq in [0,16)

    // phase 1: norms — each thread sums 16 c-rows
    const float* gb = g + (size_t)b * C_ * M_ + m0 + ml;
    float ss = 0.f;
#pragma unroll 4
    for (int i = 0; i < 16; ++i) {
        float v = gb[(size_t)(cq * 16 + i) * M_];
        ss += v * v;
    }
    red[cq][ml] = ss;
    __syncthreads();
    if (cq == 0) {
        float t = 0.f;
#pragma unroll
        for (int k = 0; k < 16; ++k) t += red[k][ml];
        sInv[ml] = 1.f / fmaxf(sqrtf(t), 1e-8f);
    }
    __syncthreads();

    unsigned short* gmc2b = gmc2 + (size_t)b * 524288 + (size_t)blockIdx.x * 16384;
    unsigned short* gcm2b = gcm2 + (size_t)b * 524288 + (size_t)blockIdx.x * 16384;

    // phase 2: casts, 4 c-tiles of 64
    for (int c0 = 0; c0 < C_; c0 += 64) {
        const float* gbase = g + ((size_t)b * C_ + c0) * M_ + m0;
        {
            int ci = tid >> 4, mq = (tid & 15) * 4;   // ci: c within tile; mq: key, %4==0
            float4 v = *(const float4*)(gbase + (size_t)ci * M_ + mq);
            uint2 pk;
            pk.x = (unsigned)f2bf(v.x) | ((unsigned)f2bf(v.y) << 16);
            pk.y = (unsigned)f2bf(v.z) | ((unsigned)f2bf(v.w) << 16);
            const int cg = c0 + ci;
            // gcm2: one (c, 4-key) chunk
            *(uint2*)(gcm2b + (cg >> 4) * 1024 + (mq >> 4) * 256 + (cg & 15) * 16 +
                      ((mq >> 2) & 3) * 4) = pk;
            T[ci * 66 + mq + 0] = f2bf(v.x * sInv[mq + 0]);
            T[ci * 66 + mq + 1] = f2bf(v.y * sInv[mq + 1]);
            T[ci * 66 + mq + 2] = f2bf(v.z * sInv[mq + 2]);
            T[ci * 66 + mq + 3] = f2bf(v.w * sInv[mq + 3]);
        }
        __syncthreads();
        if (tid < 512) {                        // 512 8-short chunks
            int mr = tid >> 3, cc8 = (tid & 7) * 8;   // mr: key; cc8: c, %8==0
            U16x8 t8;
#pragma unroll
            for (int k = 0; k < 8; ++k) t8.us[k] = T[(cc8 + k) * 66 + mr];
            const int cg = c0 + cc8;
            // gmc2: one (key, 8-c) chunk
            *(uint4*)(gmc2b + (cg >> 5) * 2048 + mr * 32 + ((cg >> 3) & 3) * 8) = t8.u4;
        }
        __syncthreads();   // T reused next tile
    }
}

// ---------------- Main fused kernel (v18) ----------------
// v17 (L2-direct, barrier-free, zero in-loop LDS) + BATCHED fragment loads:
// v17's counters showed ~5100 cyc/iter of load stall (MfmaUtil 22.6, conflicts
// 0, VALU-MFMA ~130cyc) = 24 loads x ~210cyc L2 latency SERIALIZED -- the
// compiler, pinned at the 2-waves/SIMD register ceiling (124 VGPR + 128 AGPR),
// emitted load->wait->mfma chains. v18 forces batch issue: all 8 A-frags into
// ag[8] (32 regs), GEMM1; all 16 B-frags into bv[16] (32 regs, issued before
// softmax so softmax covers their latency), GEMM2. A/B batches don't overlap
// in liveness -> peak ~244 regs, still 2 waves/SIMD. Exposed latency/iter:
// ~2x250cyc instead of 24x210.
__global__ __launch_bounds__(512, 1) void k_main(
    const float* __restrict__ l,
    const unsigned short* __restrict__ gcm2,   // fragment-linear raw   (GEMM2 B)
    const unsigned short* __restrict__ gmc2,   // fragment-linear ghat  (GEMM1 A)
    float* __restrict__ out)
{
    __shared__ __align__(16) char sMem[66560];
    float (*sDen)[64] = (float (*)[64])(sMem + 65536);         // [4 kh][64 rows]

    const int tid = threadIdx.x;
    const int w = tid >> 6;
    const int lane = tid & 63;
    const int l15 = lane & 15;
    const int quad = lane >> 4;
    const int kh = w & 3;        // key-quarter
    const int rh = w >> 2;       // row-half

    // ---- batch-clustered XCD swizzle (bijective over 256 blocks) ----
    const int bid = blockIdx.x;
    const int xcd = bid & 7;
    const int b = xcd >> 1;                                   // 2 XCDs per batch
    const int row0 = (((bid >> 3) << 1) | (xcd & 1)) * 64;    // 64-row tile in [0,4096)

    const unsigned short* gmc2_b = gmc2 + (size_t)b * 524288;
    const unsigned short* gcm2_b = gcm2 + (size_t)b * 524288;

    // ---- Q: my 32 rows (row-half rh), row norm, normalize -> bf16 B-frags ----
    short8 qf[2][8];
#pragma unroll
    for (int rt = 0; rt < 2; ++rt) {
        const float* lrow = l + ((size_t)b * N_ + row0 + rh * 32 + rt * 16 + l15) * C_;
        U16x8 qt[8];
        float ss = 0.f;
#pragma unroll
        for (int kk = 0; kk < 8; ++kk) {
            float4 x0 = *(const float4*)(lrow + kk * 32 + quad * 8);
            float4 x1 = *(const float4*)(lrow + kk * 32 + quad * 8 + 4);
            ss += x0.x*x0.x + x0.y*x0.y + x0.z*x0.z + x0.w*x0.w;
            ss += x1.x*x1.x + x1.y*x1.y + x1.z*x1.z + x1.w*x1.w;
            qt[kk].us[0] = f2bf(x0.x); qt[kk].us[1] = f2bf(x0.y);
            qt[kk].us[2] = f2bf(x0.z); qt[kk].us[3] = f2bf(x0.w);
            qt[kk].us[4] = f2bf(x1.x); qt[kk].us[5] = f2bf(x1.y);
            qt[kk].us[6] = f2bf(x1.z); qt[kk].us[7] = f2bf(x1.w);
        }
        ss += __shfl_xor(ss, 16);
        ss += __shfl_xor(ss, 32);
        const float invl = 1.0f / fmaxf(sqrtf(ss), 1e-8f);
#pragma unroll
        for (int kk = 0; kk < 8; ++kk) {
            U16x8 t;
#pragma unroll
            for (int j = 0; j < 8; ++j) t.us[j] = f2bf(bf2f(qt[kk].us[j]) * invl);
            qf[rt][kk] = t.s8;
        }
    }

    f32x4 zero = {0.f, 0.f, 0.f, 0.f};
    f32x4 o[2][16];    // per-wave PARTIAL O (its 16 keys): [row-tile][c-tile 16c]
#pragma unroll
    for (int i = 0; i < 2; ++i)
#pragma unroll
        for (int j = 0; j < 16; ++j) o[i][j] = zero;
    float dl0 = 0.f, dl1 = 0.f;

    // fragment-linear per-lane bases (see k_prep header comment)
    const unsigned short* gAbase = gmc2_b + (kh * 16 + l15) * 32 + quad * 8;   // + mt*16384 + kk*2048
    const unsigned short* gBbase = gcm2_b + kh * 256 + l15 * 16 + quad * 4;    // + mt*16384 + ct*1024

    // ---- barrier-free main loop over 32 key-tiles ----
    for (int mt = 0; mt < 32; ++mt) {
        const unsigned short* gA = gAbase + (size_t)mt * 16384;
        const unsigned short* gB = gBbase + (size_t)mt * 16384;

        // batch-issue all 8 A-frags (one latency for the batch, not per load)
        short8 ag[8];
#pragma unroll
        for (int kk = 0; kk < 8; ++kk) ag[kk] = *(const short8*)&gA[kk * 2048];

        // GEMM1 (swapped): S^T[16 keys][16 rows] per row-tile, K=256
        f32x4 sa0 = zero, sa1 = zero;
#pragma unroll
        for (int kk = 0; kk < 8; ++kk) {
            sa0 = __builtin_amdgcn_mfma_f32_16x16x32_bf16(ag[kk], qf[0][kk], sa0, 0, 0, 0);
            sa1 = __builtin_amdgcn_mfma_f32_16x16x32_bf16(ag[kk], qf[1][kk], sa1, 0, 0, 0);
        }

        // batch-issue all 16 B-frags; softmax below covers their latency
        short4v bv[16];
#pragma unroll
        for (int ct = 0; ct < 16; ++ct) bv[ct] = *(const short4v*)&gB[ct * 1024];

        // p = exp(cos/tau); lane holds (q-row = l15, key = quad*4+r) -> already
        // the 16x16x16 A-frag layout. Accumulate denominator partials.
        U16x4 pk0, pk1;
#pragma unroll
        for (int r = 0; r < 4; ++r) {
            float p0 = exp2f(sa0[r] * 3.6067376022224085f);
            float p1 = exp2f(sa1[r] * 3.6067376022224085f);
            dl0 += p0; dl1 += p1;
            pk0.us[r] = f2bf(p0);
            pk1.us[r] = f2bf(p1);
        }

        // GEMM2 key-split: O_partial[32 rows][256 c] += P[32][16 keys] * V[16][256]
#pragma unroll
        for (int ct = 0; ct < 16; ++ct) {
            o[0][ct] = mfma16x16(pk0.s4, bv[ct], o[0][ct]);
            o[1][ct] = mfma16x16(pk1.s4, bv[ct], o[1][ct]);
        }
    }

    // ---- denominators: quad-reduce, publish per key-quarter per row ----
    {
        float d0 = dl0;
        d0 += __shfl_xor(d0, 16);
        d0 += __shfl_xor(d0, 32);
        float d1 = dl1;
        d1 += __shfl_xor(d1, 16);
        d1 += __shfl_xor(d1, 32);
        if (quad == 0) {
            sDen[kh][rh * 32 + l15] = d0;
            sDen[kh][rh * 32 + 16 + l15] = d1;
        }
    }

    // ---- O reduction: 4 static rounds (rh x rt) through 64 KB LDS dump ----
    // slot(kh', j, quad, l15) = kh'*1024 + j*64 + quad*16 + l15  (f32x4 units)
    // All indices static (rule #20). red4 covers sMem[0,65536); sDen at 65536.
    f32x4* red4 = (f32x4*)sMem;
    const int wslot = kh * 1024 + quad * 16 + l15;       // + j*64
    const int rslot = (4 * kh) * 64 + quad * 16 + l15;   // + jj*64 + kh'*1024
    f32x4 oacc0[4], oacc1[4];

#define RED_ROUND(RH, OSRC, ODST)                                              \
    __syncthreads();                                                           \
    if (rh == (RH)) {                                                          \
        _Pragma("unroll")                                                      \
        for (int j = 0; j < 16; ++j) red4[wslot + j * 64] = OSRC[j];           \
    }                                                                          \
    __syncthreads();                                                           \
    if (rh == (RH)) {                                                          \
        _Pragma("unroll")                                                      \
        for (int jj = 0; jj < 4; ++jj) {                                       \
            const int base = rslot + jj * 64;                                  \
            ODST[jj] = red4[base] + red4[base + 1024] +                        \
                       red4[base + 2048] + red4[base + 3072];                  \
        }                                                                      \
    }

    RED_ROUND(0, o[0], oacc0)
    RED_ROUND(0, o[1], oacc1)
    RED_ROUND(1, o[0], oacc0)
    RED_ROUND(1, o[1], oacc1)
#undef RED_ROUND

    // ---- epilogue: wave (kh, rh) owns rows [32rh,32rh+32), c [64kh, 64kh+64) ----
    const float* lb = l + ((size_t)b * N_ + row0 + rh * 32) * C_;
    float* ob = out + ((size_t)b * N_ + row0 + rh * 32) * C_;
#pragma unroll
    for (int r = 0; r < 4; ++r) {
        {   // row-tile 0
            const int row = quad * 4 + r;
            const int grow = rh * 32 + row;
            const float inv = 1.f / (sDen[0][grow] + sDen[1][grow] + sDen[2][grow] + sDen[3][grow]);
            const size_t rb = (size_t)row * C_;
#pragma unroll
            for (int jj = 0; jj < 4; ++jj) {
                const int c = kh * 64 + jj * 16 + l15;
                ob[rb + c] = lb[rb + c] + oacc0[jj][r] * inv;
            }
        }
        {   // row-tile 1
            const int row = 16 + quad * 4 + r;
            const int grow = rh * 32 + row;
            const float inv = 1.f / (sDen[0][grow] + sDen[1][grow] + sDen[2][grow] + sDen[3][grow]);
            const size_t rb = (size_t)row * C_;
#pragma unroll
            for (int jj = 0; jj < 4; ++jj) {
                const int c = kh * 64 + jj * 16 + l15;
                ob[rb + c] = lb[rb + c] + oacc1[jj][r] * inv;
            }
        }
    }
}

extern "C" void kernel_launch(void* const* d_in, const int* in_sizes, int n_in,
                              void* d_out, int out_size, void* d_ws, size_t ws_size,
                              hipStream_t stream) {
    (void)in_sizes; (void)n_in; (void)out_size; (void)ws_size;
    const float* l = (const float*)d_in[0];
    const float* g = (const float*)d_in[1];
    float* outp = (float*)d_out;

    char* ws = (char*)d_ws;
    unsigned short* gmc2 = (unsigned short*)ws;                                  // 4 MB (fragment-linear ghat)
    unsigned short* gcm2 = (unsigned short*)(ws + (size_t)B_ * M_ * C_ * 2);     // 4 MB (fragment-linear raw)

    k_prep<<<dim3(M_ / 64, B_), 1024, 0, stream>>>(g, gcm2, gmc2);
    k_main<<<dim3(N_ / 64 * B_), 512, 0, stream>>>(l, gcm2, gmc2, outp);
}

// Round 15
// 138.927 us; speedup vs baseline: 1.1483x; 1.1483x over previous
//
#include <hip/hip_runtime.h>

#define B_ 4
#define N_ 4096
#define C_ 256
#define M_ 2048

typedef __attribute__((ext_vector_type(8))) short short8;
typedef __attribute__((ext_vector_type(4))) float f32x4;

union U16x8 { uint4 u4; unsigned short us[8]; short8 s8; };
union U16x4 { uint2 u2; unsigned short us[4]; };

__device__ __forceinline__ float bf2f(unsigned short h) {
    unsigned int u = ((unsigned int)h) << 16;
    return __builtin_bit_cast(float, u);
}
__device__ __forceinline__ unsigned short f2bf(float f) {
    unsigned int u = __builtin_bit_cast(unsigned int, f);
    u += 0x7FFFu + ((u >> 16) & 1u);
    return (unsigned short)(u >> 16);
}

#define GLB_AS(p) ((const __attribute__((address_space(1))) unsigned int*)(p))
#define LDS_AS(p) ((__attribute__((address_space(3))) unsigned int*)(p))

// ---- Fused prepass: norms + casts. gmc (GEMM1 A, [m][c] normalized) unchanged
// from v13. gcm3 (GEMM2 B) is PAIR-INTERLEAVED fragment-linear:
//   short-offset = pair*32768 + kh*8192 + ct*512 + kq*128 + cr*8 + parity*4 + r
//   content: graw[c=ct*16+cr][key = (2*pair+parity)*64 + kh*16 + kq*4 + r]
// so k_main's B-frag = ONE b128 at (kh, quad=kq, l15=cr, ct): us[j] = j<4 ?
// V_even : V_odd -- matching the 16x16x32 A-frag k=quad*8+j with packed
// {pkE,pkO}.
__global__ __launch_bounds__(1024) void k_prep(const float* __restrict__ g,
                                               unsigned short* __restrict__ gcm3,
                                               unsigned short* __restrict__ gmc) {
    __shared__ float red[16][64];
    __shared__ float sInv[64];
    __shared__ unsigned short T[64 * 66];   // normalized [c][m] tile, odd-dword stride
    const int t = blockIdx.x;                   // 64-key tile index
    const int b = blockIdx.y, m0 = t * 64;
    const int tid = threadIdx.x;                // 0..1023
    const int ml = tid & 63, cq = tid >> 6;     // cq in [0,16)

    // phase 1: norms — each thread sums 16 c-rows
    const float* gb = g + (size_t)b * C_ * M_ + m0 + ml;
    float ss = 0.f;
#pragma unroll 4
    for (int i = 0; i < 16; ++i) {
        float v = gb[(size_t)(cq * 16 + i) * M_];
        ss += v * v;
    }
    red[cq][ml] = ss;
    __syncthreads();
    if (cq == 0) {
        float t0 = 0.f;
#pragma unroll
        for (int k = 0; k < 16; ++k) t0 += red[k][ml];
        sInv[ml] = 1.f / fmaxf(sqrtf(t0), 1e-8f);
    }
    __syncthreads();

    unsigned short* gmcb = gmc + ((size_t)b * M_ + m0) * C_;     // [m][c] rows
    unsigned short* gcm3b = gcm3 + (size_t)b * 524288 +
                            (size_t)(t >> 1) * 32768 + (t & 1) * 4;

    // phase 2: casts, 4 c-tiles of 64
    for (int c0 = 0; c0 < C_; c0 += 64) {
        const float* gbase = g + ((size_t)b * C_ + c0) * M_ + m0;
        {
            int ci = tid >> 4, mq = (tid & 15) * 4;   // ci: c within tile; mq: key
            float4 v = *(const float4*)(gbase + (size_t)ci * M_ + mq);
            uint2 pk;
            pk.x = (unsigned)f2bf(v.x) | ((unsigned)f2bf(v.y) << 16);
            pk.y = (unsigned)f2bf(v.z) | ((unsigned)f2bf(v.w) << 16);
            const int cg = c0 + ci;
            const int kh = mq >> 4, kq = (mq >> 2) & 3;
            // gcm3: 4 keys (r=0..3) x one channel, 8B contiguous
            *(uint2*)(gcm3b + kh * 8192 + (cg >> 4) * 512 + kq * 128 +
                      (cg & 15) * 8) = pk;
            T[ci * 66 + mq + 0] = f2bf(v.x * sInv[mq + 0]);
            T[ci * 66 + mq + 1] = f2bf(v.y * sInv[mq + 1]);
            T[ci * 66 + mq + 2] = f2bf(v.z * sInv[mq + 2]);
            T[ci * 66 + mq + 3] = f2bf(v.w * sInv[mq + 3]);
        }
        __syncthreads();
        if (tid < 512) {                        // 512 8-short chunks
            int mr = tid >> 3, cc8 = (tid & 7) * 8;
            U16x8 t8;
#pragma unroll
            for (int k = 0; k < 8; ++k) t8.us[k] = T[(cc8 + k) * 66 + mr];
            *(uint4*)(gmcb + (size_t)mr * C_ + c0 + cc8) = t8.u4;
        }
        __syncthreads();   // T reused next tile
    }
}

// ---------------- Main fused kernel (v19b) ----------------
// v13 structure with tiles processed in PAIRS (16 outer iters):
//   G1(even tile) -> pkE ; G1(odd tile) -> pkO ; barrier A ; dmaA(next pair) ;
//   G2 with K=32 MFMA: A-frag = {pkE, pkO} packed in regs (the 16x16x32 A
//   layout k=quad*8+j IS the concatenation of two tiles' quad*4+r -- zero
//   shuffles) ; barrier B ; dmaB(next pair).
// Per pair per wave vs v13: MFMA 96->64 instrs, LDS reads 48->32 (all b128,
// B conflict-free lane-linear), barriers 4->2, DMA volume unchanged, +4 VGPR.
// A-path (sGmc XOR swizzle, G1 math) byte-identical to v13, in 2 regions.
// v19b fixes v19's G2 read base: kh stride in gcm3 layout is 8192 shorts
// (16 ct x 512), not 4096 -- caught in round-14 audit before HW exposure.
__global__ __launch_bounds__(512, 1) void k_main(
    const float* __restrict__ l,
    const unsigned short* __restrict__ gcm3,   // pair-interleaved raw (GEMM2 B)
    const unsigned short* __restrict__ gmc,    // [B][M][C] normalized (GEMM1 A)
    float* __restrict__ out)
{
    __shared__ __align__(16) char sMem[132096];
    unsigned short* sGmcD = (unsigned short*)sMem;             // ghat [2][64][256], 64 KB
    unsigned short* sGcm3 = (unsigned short*)(sMem + 65536);   // V pair-frag, 64 KB
    float (*sDen)[64] = (float (*)[64])(sMem + 131072);        // [4 kh][64 rows]

    const int tid = threadIdx.x;
    const int w = tid >> 6;
    const int lane = tid & 63;
    const int l15 = lane & 15;
    const int quad = lane >> 4;
    const int kh = w & 3;        // key-quarter
    const int rh = w >> 2;       // row-half

    // ---- batch-clustered XCD swizzle (bijective over 256 blocks) ----
    const int bid = blockIdx.x;
    const int xcd = bid & 7;
    const int b = xcd >> 1;                                   // 2 XCDs per batch
    const int row0 = (((bid >> 3) << 1) | (xcd & 1)) * 64;    // 64-row tile in [0,4096)

    // A-side DMA offsets: v13's XOR chunk swizzle (unchanged)
    int goffA[4];
#pragma unroll
    for (int i = 0; i < 4; ++i) {
        int p = (w * 4 + i) * 64 + lane;                   // p in [0,2048)
        int rA = p >> 5;                                   // row in [0,64)
        goffA[i] = rA * 256 + (((p & 31) ^ (rA & 31)) << 3);
    }

    const unsigned short* gmc_b = gmc + (size_t)b * M_ * C_;
    const unsigned short* gcm3_b = gcm3 + (size_t)b * 524288;

    // tile = 64-key tile index; reg = sGmc region (0/1)
    auto dmaA = [&](int tile, int reg) {
#pragma unroll
        for (int i = 0; i < 4; ++i)
            __builtin_amdgcn_global_load_lds(GLB_AS(gmc_b + (size_t)tile * 16384 + goffA[i]),
                                             LDS_AS(&sGmcD[reg * 16384 + (w * 4 + i) * 512]), 16, 0, 0);
    };
    // pair = tile pair index; identity copy (gcm3 is pre-arranged to LDS order)
    auto dmaB = [&](int pair) {
#pragma unroll
        for (int i = 0; i < 8; ++i)
            __builtin_amdgcn_global_load_lds(GLB_AS(gcm3_b + (size_t)pair * 32768 + (w * 8 + i) * 512 + lane * 8),
                                             LDS_AS(&sGcm3[(w * 8 + i) * 512]), 16, 0, 0);
    };

    // stage pair 0
    dmaA(0, 0);
    dmaA(1, 1);
    dmaB(0);

    // ---- Q: my 32 rows (row-half rh), row norm, normalize -> bf16 B-frags ----
    short8 qf[2][8];
#pragma unroll
    for (int rt = 0; rt < 2; ++rt) {
        const float* lrow = l + ((size_t)b * N_ + row0 + rh * 32 + rt * 16 + l15) * C_;
        U16x8 qt[8];
        float ss = 0.f;
#pragma unroll
        for (int kk = 0; kk < 8; ++kk) {
            float4 x0 = *(const float4*)(lrow + kk * 32 + quad * 8);
            float4 x1 = *(const float4*)(lrow + kk * 32 + quad * 8 + 4);
            ss += x0.x*x0.x + x0.y*x0.y + x0.z*x0.z + x0.w*x0.w;
            ss += x1.x*x1.x + x1.y*x1.y + x1.z*x1.z + x1.w*x1.w;
            qt[kk].us[0] = f2bf(x0.x); qt[kk].us[1] = f2bf(x0.y);
            qt[kk].us[2] = f2bf(x0.z); qt[kk].us[3] = f2bf(x0.w);
            qt[kk].us[4] = f2bf(x1.x); qt[kk].us[5] = f2bf(x1.y);
            qt[kk].us[6] = f2bf(x1.z); qt[kk].us[7] = f2bf(x1.w);
        }
        ss += __shfl_xor(ss, 16);
        ss += __shfl_xor(ss, 32);
        const float invl = 1.0f / fmaxf(sqrtf(ss), 1e-8f);
#pragma unroll
        for (int kk = 0; kk < 8; ++kk) {
            U16x8 t;
#pragma unroll
            for (int j = 0; j < 8; ++j) t.us[j] = f2bf(bf2f(qt[kk].us[j]) * invl);
            qf[rt][kk] = t.s8;
        }
    }

    __syncthreads();   // drains pair-0 staging

    f32x4 zero = {0.f, 0.f, 0.f, 0.f};
    f32x4 o[2][16];    // per-wave PARTIAL O (its 16 keys): [row-tile][c-tile 16c]
#pragma unroll
    for (int i = 0; i < 2; ++i)
#pragma unroll
        for (int j = 0; j < 16; ++j) o[i][j] = zero;
    float dl0 = 0.f, dl1 = 0.f;

    // GEMM1 A-frag source: my 16 key-rows (region offset added per parity)
    const unsigned short* gAbase = &sGmcD[(kh * 16 + l15) * 256];
    const int rxor = (kh * 16 + l15) & 31;
    // GEMM2 B-frag source: lane-linear (conflict-free). kh stride = 8192 shorts.
    const unsigned short* gB3 = &sGcm3[kh * 8192 + quad * 128 + l15 * 8];

    for (int p = 0; p < 16; ++p) {
        U16x4 pkE0, pkE1, pkO0, pkO1;

        // ---- G1 even tile (region 0) ----
        {
            f32x4 sa0 = zero, sa1 = zero;
#pragma unroll
            for (int kk = 0; kk < 8; ++kk) {
                short8 ag = *(const short8*)&gAbase[((kk * 4 + quad) ^ rxor) << 3];
                sa0 = __builtin_amdgcn_mfma_f32_16x16x32_bf16(ag, qf[0][kk], sa0, 0, 0, 0);
                sa1 = __builtin_amdgcn_mfma_f32_16x16x32_bf16(ag, qf[1][kk], sa1, 0, 0, 0);
            }
#pragma unroll
            for (int r = 0; r < 4; ++r) {
                float p0 = exp2f(sa0[r] * 3.6067376022224085f);
                float p1 = exp2f(sa1[r] * 3.6067376022224085f);
                dl0 += p0; dl1 += p1;
                pkE0.us[r] = f2bf(p0);
                pkE1.us[r] = f2bf(p1);
            }
        }
        // ---- G1 odd tile (region 1) ----
        {
            f32x4 sa0 = zero, sa1 = zero;
#pragma unroll
            for (int kk = 0; kk < 8; ++kk) {
                short8 ag = *(const short8*)&gAbase[16384 + (((kk * 4 + quad) ^ rxor) << 3)];
                sa0 = __builtin_amdgcn_mfma_f32_16x16x32_bf16(ag, qf[0][kk], sa0, 0, 0, 0);
                sa1 = __builtin_amdgcn_mfma_f32_16x16x32_bf16(ag, qf[1][kk], sa1, 0, 0, 0);
            }
#pragma unroll
            for (int r = 0; r < 4; ++r) {
                float p0 = exp2f(sa0[r] * 3.6067376022224085f);
                float p1 = exp2f(sa1[r] * 3.6067376022224085f);
                dl0 += p0; dl1 += p1;
                pkO0.us[r] = f2bf(p0);
                pkO1.us[r] = f2bf(p1);
            }
        }

        __syncthreads();                    // barrier A: sGmc reads done, dmaB drained
        if (p < 15) { dmaA(2 * p + 2, 0); dmaA(2 * p + 3, 1); }   // covered by G2

        // ---- G2 with K=32: A = {pkE, pkO} packed (k = quad*8+j) ----
        U16x8 ap0, ap1;
#pragma unroll
        for (int r = 0; r < 4; ++r) {
            ap0.us[r] = pkE0.us[r]; ap0.us[4 + r] = pkO0.us[r];
            ap1.us[r] = pkE1.us[r]; ap1.us[4 + r] = pkO1.us[r];
        }
#pragma unroll
        for (int ct = 0; ct < 16; ++ct) {
            U16x8 bb;
            bb.u4 = *(const uint4*)&gB3[ct * 512];
            o[0][ct] = __builtin_amdgcn_mfma_f32_16x16x32_bf16(ap0.s8, bb.s8, o[0][ct], 0, 0, 0);
            o[1][ct] = __builtin_amdgcn_mfma_f32_16x16x32_bf16(ap1.s8, bb.s8, o[1][ct], 0, 0, 0);
        }

        __syncthreads();                    // barrier B: sGcm3 reads done, dmaA drained
        if (p < 15) dmaB(p + 1);            // covered by next pair's G1s
    }

    // ---- denominators: quad-reduce, publish per key-quarter per row ----
    {
        float d0 = dl0;
        d0 += __shfl_xor(d0, 16);
        d0 += __shfl_xor(d0, 32);
        float d1 = dl1;
        d1 += __shfl_xor(d1, 16);
        d1 += __shfl_xor(d1, 32);
        if (quad == 0) {
            sDen[kh][rh * 32 + l15] = d0;
            sDen[kh][rh * 32 + 16 + l15] = d1;
        }
    }

    // ---- O reduction: 4 static rounds (rh x rt) through 64 KB LDS dump ----
    // All indices static (rule #20). red4 covers sMem[0,65536); sDen at 131072.
    f32x4* red4 = (f32x4*)sMem;
    const int wslot = kh * 1024 + quad * 16 + l15;       // + j*64
    const int rslot = (4 * kh) * 64 + quad * 16 + l15;   // + jj*64 + kh'*1024
    f32x4 oacc0[4], oacc1[4];

#define RED_ROUND(RH, OSRC, ODST)                                              \
    __syncthreads();                                                           \
    if (rh == (RH)) {                                                          \
        _Pragma("unroll")                                                      \
        for (int j = 0; j < 16; ++j) red4[wslot + j * 64] = OSRC[j];           \
    }                                                                          \
    __syncthreads();                                                           \
    if (rh == (RH)) {                                                          \
        _Pragma("unroll")                                                      \
        for (int jj = 0; jj < 4; ++jj) {                                       \
            const int base = rslot + jj * 64;                                  \
            ODST[jj] = red4[base] + red4[base + 1024] +                        \
                       red4[base + 2048] + red4[base + 3072];                  \
        }                                                                      \
    }

    RED_ROUND(0, o[0], oacc0)
    RED_ROUND(0, o[1], oacc1)
    RED_ROUND(1, o[0], oacc0)
    RED_ROUND(1, o[1], oacc1)
#undef RED_ROUND

    // ---- epilogue: wave (kh, rh) owns rows [32rh,32rh+32), c [64kh, 64kh+64) ----
    const float* lb = l + ((size_t)b * N_ + row0 + rh * 32) * C_;
    float* ob = out + ((size_t)b * N_ + row0 + rh * 32) * C_;
#pragma unroll
    for (int r = 0; r < 4; ++r) {
        {   // row-tile 0
            const int row = quad * 4 + r;
            const int grow = rh * 32 + row;
            const float inv = 1.f / (sDen[0][grow] + sDen[1][grow] + sDen[2][grow] + sDen[3][grow]);
            const size_t rb = (size_t)row * C_;
#pragma unroll
            for (int jj = 0; jj < 4; ++jj) {
                const int c = kh * 64 + jj * 16 + l15;
                ob[rb + c] = lb[rb + c] + oacc0[jj][r] * inv;
            }
        }
        {   // row-tile 1
            const int row = 16 + quad * 4 + r;
            const int grow = rh * 32 + row;
            const float inv = 1.f / (sDen[0][grow] + sDen[1][grow] + sDen[2][grow] + sDen[3][grow]);
            const size_t rb = (size_t)row * C_;
#pragma unroll
            for (int jj = 0; jj < 4; ++jj) {
                const int c = kh * 64 + jj * 16 + l15;
                ob[rb + c] = lb[rb + c] + oacc1[jj][r] * inv;
            }
        }
    }
}

extern "C" void kernel_launch(void* const* d_in, const int* in_sizes, int n_in,
                              void* d_out, int out_size, void* d_ws, size_t ws_size,
                              hipStream_t stream) {
    (void)in_sizes; (void)n_in; (void)out_size; (void)ws_size;
    const float* l = (const float*)d_in[0];
    const float* g = (const float*)d_in[1];
    float* outp = (float*)d_out;

    char* ws = (char*)d_ws;
    unsigned short* gmc = (unsigned short*)ws;                                   // 4 MB (normalized, [b][m][c])
    unsigned short* gcm3 = (unsigned short*)(ws + (size_t)B_ * M_ * C_ * 2);     // 4 MB (pair-frag raw)

    k_prep<<<dim3(M_ / 64, B_), 1024, 0, stream>>>(g, gcm3, gmc);
    k_main<<<dim3(N_ / 64 * B_), 512, 0, stream>>>(l, gcm3, gmc, outp);
}